// Round 1
// baseline (1911.512 us; speedup 1.0000x reference)
//
#include <hip/hip_runtime.h>

#define TK 128
#define TH 8
#define TB 4
#define TT 2048
#define NM (TT*TH)     // 16384 rows (m = t*8+h) per batch
#define KH 1024        // K*H output channels
#define KSZ 5

typedef unsigned int u32;
typedef unsigned short u16;

// ---- bf16 <-> f32 helpers (bit-level, no hip_bf16 API dependency) ----
__device__ __forceinline__ u16 f2bf(float f) {
  u32 u = __float_as_uint(f);
  u32 r = u + 0x7fffu + ((u >> 16) & 1u);   // round-to-nearest-even
  return (u16)(r >> 16);
}
__device__ __forceinline__ float bf2f(u16 h) {
  return __uint_as_float(((u32)h) << 16);
}
__device__ __forceinline__ float2 bfp2f(u32 u) {   // packed pair -> 2 floats
  return make_float2(__uint_as_float(u << 16), __uint_as_float(u & 0xffff0000u));
}
__device__ __forceinline__ u32 f2bfp(float lo, float hi) {
  return ((u32)f2bf(lo)) | (((u32)f2bf(hi)) << 16);
}

// ============================================================
// Kernel 0: weight transposes (channel-last for coalesced reads)
//   Wqt[(i*5+j)*1024 + o] = Wq[o][i][j]   (same Wk)
//   Wvt[i*1024 + o]       = Wv[o][i]
//   Wut[c*128 + kk]       = Wu[kk][c]
// ============================================================
__global__ void prep_kernel(const float* __restrict__ Wq, const float* __restrict__ Wk,
                            const float* __restrict__ Wv, const float* __restrict__ Wu,
                            float* __restrict__ Wqt, float* __restrict__ Wkt,
                            float* __restrict__ Wvt, float* __restrict__ Wut) {
  int idx = blockIdx.x * 256 + threadIdx.x;      // grid covers 640*1024 exactly
  int ij = idx >> 10;
  int o  = idx & 1023;
  Wqt[idx] = Wq[o * (TK * KSZ) + ij];
  Wkt[idx] = Wk[o * (TK * KSZ) + ij];
  if (idx < TK * KH) {
    int i2 = idx >> 10;
    Wvt[idx] = Wv[o * TK + i2];
    int c = idx >> 7, kk = idx & 127;
    Wut[idx] = Wu[kk * KH + c];
  }
}

// ============================================================
// Kernel 1: causal conv QKV -> bf16 tensors in m-layout
//   Qm[b][m=t*8+h][d] = (conv_q[b][o=d*8+h][t] + bq)/scale ; K same; V tap-1 no bias/scale
// Block: 256 thr, 32 t-values, half of the 1024 channels. Grid (64, 2, 4).
// ============================================================
__device__ __forceinline__ void conv5_pass(
    const float (*xs)[TK], u16* ys, const float* __restrict__ Wt,
    const float* __restrict__ bias, u16* __restrict__ dst,
    float outscale, int tid, int half, int t0, int b) {
  const int oc0 = half * 512 + tid;
  float acc[2][32];
#pragma unroll
  for (int c = 0; c < 2; ++c) {
    float bv = bias[oc0 + c * 256];
#pragma unroll
    for (int t = 0; t < 32; ++t) acc[c][t] = bv;
  }
  for (int i = 0; i < TK; ++i) {
    float xv[36];
#pragma unroll
    for (int r = 0; r < 36; ++r) xv[r] = xs[r][i];
#pragma unroll
    for (int c = 0; c < 2; ++c) {
      const float* wp = Wt + (size_t)(i * KSZ) * KH + oc0 + c * 256;
#pragma unroll
      for (int j = 0; j < KSZ; ++j) {
        float w = wp[j * KH];
#pragma unroll
        for (int t = 0; t < 32; ++t) acc[c][t] += xv[t + j] * w;
      }
    }
  }
  // stage transposed tile: ys[(t*8+h)][d_local]
#pragma unroll
  for (int c = 0; c < 2; ++c) {
    int oc = oc0 + c * 256;
    int dl = (oc >> 3) - half * 64, h = oc & 7;
#pragma unroll
    for (int t = 0; t < 32; ++t)
      ys[(t * 8 + h) * 64 + dl] = f2bf(acc[c][t] * outscale);
  }
  __syncthreads();
  const uint4* ysv = reinterpret_cast<const uint4*>(ys);
  for (int li = tid; li < 2048; li += 256) {
    int row = li >> 3, dcol = (li & 7) * 8;
    *reinterpret_cast<uint4*>(dst + ((size_t)b * NM + t0 * 8 + row) * TK + half * 64 + dcol) = ysv[li];
  }
  __syncthreads();
}

__device__ __forceinline__ void conv1_pass(
    const float (*xs)[TK], u16* ys, const float* __restrict__ Wt,
    u16* __restrict__ dst, int tid, int half, int t0, int b) {
  const int oc0 = half * 512 + tid;
  float acc[2][32];
#pragma unroll
  for (int c = 0; c < 2; ++c)
#pragma unroll
    for (int t = 0; t < 32; ++t) acc[c][t] = 0.0f;
  for (int i = 0; i < TK; ++i) {
    float xv[32];
#pragma unroll
    for (int r = 0; r < 32; ++r) xv[r] = xs[r + 4][i];
#pragma unroll
    for (int c = 0; c < 2; ++c) {
      float w = Wt[(size_t)i * KH + oc0 + c * 256];
#pragma unroll
      for (int t = 0; t < 32; ++t) acc[c][t] += xv[t] * w;
    }
  }
#pragma unroll
  for (int c = 0; c < 2; ++c) {
    int oc = oc0 + c * 256;
    int dl = (oc >> 3) - half * 64, h = oc & 7;
#pragma unroll
    for (int t = 0; t < 32; ++t)
      ys[(t * 8 + h) * 64 + dl] = f2bf(acc[c][t]);
  }
  __syncthreads();
  const uint4* ysv = reinterpret_cast<const uint4*>(ys);
  for (int li = tid; li < 2048; li += 256) {
    int row = li >> 3, dcol = (li & 7) * 8;
    *reinterpret_cast<uint4*>(dst + ((size_t)b * NM + t0 * 8 + row) * TK + half * 64 + dcol) = ysv[li];
  }
  __syncthreads();
}

__global__ __launch_bounds__(256) void qkv_kernel(
    const float* __restrict__ x,
    const float* __restrict__ Wqt, const float* __restrict__ bq,
    const float* __restrict__ Wkt, const float* __restrict__ bk,
    const float* __restrict__ Wvt,
    u16* __restrict__ Qm, u16* __restrict__ Km, u16* __restrict__ Vm) {
  const int tid = threadIdx.x;
  const int t0 = blockIdx.x * 32;
  const int half = blockIdx.y;
  const int b = blockIdx.z;

  __shared__ float xs[36][TK];        // rows t0-4 .. t0+31
  __shared__ u16 ys[256 * 64];        // transpose-stage buffer

  for (int li = tid; li < 36 * TK; li += 256) {
    int rr = li >> 7, col = li & 127;
    int t = t0 - 4 + rr;
    xs[rr][col] = (t >= 0) ? x[((size_t)b * TT + t) * TK + col] : 0.0f;
  }
  __syncthreads();

  const float inv_scale = 0.29730177875068026f;   // 128^-0.25
  conv5_pass(xs, ys, Wqt, bq, Qm, inv_scale, tid, half, t0, b);
  conv5_pass(xs, ys, Wkt, bk, Km, inv_scale, tid, half, t0, b);
  conv1_pass(xs, ys, Wvt, Vm, tid, half, t0, b);
}

// ============================================================
// Kernel 2: flash attention over contiguous 2048-row chunks.
// Block: 256 thr = 16x16 (ti,tj); 64 q-rows per block, 64-key tiles.
// LDS row strides: q/k/v 67 uints (134 bf16) -> worst 2-way bank alias (free).
// ============================================================
#define SST 67   // uint stride of q/k/v LDS rows
#define PST 36   // uint stride of p LDS rows

__global__ __launch_bounds__(256) void attn_kernel(
    const u16* __restrict__ Qm, const u16* __restrict__ Km,
    const u16* __restrict__ Vm, u16* __restrict__ Om) {
  const int tid = threadIdx.x;
  const int it = 31 - (int)blockIdx.x;   // big blocks first (tail balance)
  const int gp = blockIdx.y;
  const int b  = blockIdx.z;
  const size_t base = (size_t)b * NM + (size_t)gp * TT;
  const int i0 = it * 64;

  __shared__ u32 qs[64 * SST];
  __shared__ u32 ks[64 * SST];
  __shared__ u32 vs[64 * SST];
  __shared__ u32 ps[64 * PST];

  {
    const u32* src = reinterpret_cast<const u32*>(Qm + (base + i0) * TK);
    for (int li = tid; li < 4096; li += 256) {
      int row = li >> 6, cp = li & 63;
      qs[row * SST + cp] = src[row * 64 + cp];
    }
  }

  const int ti = tid >> 4, tj = tid & 15;
  float m_r[4], l_r[4], o_acc[4][8];
#pragma unroll
  for (int r = 0; r < 4; ++r) {
    m_r[r] = -1e30f; l_r[r] = 0.0f;
#pragma unroll
    for (int cc = 0; cc < 8; ++cc) o_acc[r][cc] = 0.0f;
  }

  for (int jt = 0; jt <= it; ++jt) {
    __syncthreads();
    {
      const int j0 = jt * 64;
      const u32* ksrc = reinterpret_cast<const u32*>(Km + (base + j0) * TK);
      const u32* vsrc = reinterpret_cast<const u32*>(Vm + (base + j0) * TK);
      for (int li = tid; li < 4096; li += 256) {
        int row = li >> 6, cp = li & 63;
        ks[row * SST + cp] = ksrc[row * 64 + cp];
        vs[row * SST + cp] = vsrc[row * 64 + cp];
      }
    }
    __syncthreads();

    // S = Q K^T  (4x4 fragment per thread)
    float s[4][4];
#pragma unroll
    for (int r = 0; r < 4; ++r)
#pragma unroll
      for (int c = 0; c < 4; ++c) s[r][c] = 0.0f;

    for (int d2 = 0; d2 < 64; ++d2) {
      float2 qv[4], kv[4];
#pragma unroll
      for (int r = 0; r < 4; ++r) qv[r] = bfp2f(qs[(ti * 4 + r) * SST + d2]);
#pragma unroll
      for (int c = 0; c < 4; ++c) kv[c] = bfp2f(ks[(tj * 4 + c) * SST + d2]);
#pragma unroll
      for (int r = 0; r < 4; ++r)
#pragma unroll
        for (int c = 0; c < 4; ++c)
          s[r][c] += qv[r].x * kv[c].x + qv[r].y * kv[c].y;
    }

    if (jt == it) {   // diagonal tile: mask j > i (local == global condition)
#pragma unroll
      for (int r = 0; r < 4; ++r)
#pragma unroll
        for (int c = 0; c < 4; ++c)
          if (tj * 4 + c > ti * 4 + r) s[r][c] = -1e30f;
    }

    // online softmax (row groups of 16 lanes share a row set)
#pragma unroll
    for (int r = 0; r < 4; ++r) {
      float tm = fmaxf(fmaxf(s[r][0], s[r][1]), fmaxf(s[r][2], s[r][3]));
      tm = fmaxf(tm, __shfl_xor(tm, 1));
      tm = fmaxf(tm, __shfl_xor(tm, 2));
      tm = fmaxf(tm, __shfl_xor(tm, 4));
      tm = fmaxf(tm, __shfl_xor(tm, 8));
      float mnew = fmaxf(m_r[r], tm);
      float alpha = __expf(m_r[r] - mnew);
      float p[4], psum = 0.0f;
#pragma unroll
      for (int c = 0; c < 4; ++c) { p[c] = __expf(s[r][c] - mnew); psum += p[c]; }
      psum += __shfl_xor(psum, 1);
      psum += __shfl_xor(psum, 2);
      psum += __shfl_xor(psum, 4);
      psum += __shfl_xor(psum, 8);
      l_r[r] = l_r[r] * alpha + psum;
      m_r[r] = mnew;
#pragma unroll
      for (int cc = 0; cc < 8; ++cc) o_acc[r][cc] *= alpha;
      ps[(ti * 4 + r) * PST + tj * 2]     = f2bfp(p[0], p[1]);
      ps[(ti * 4 + r) * PST + tj * 2 + 1] = f2bfp(p[2], p[3]);
    }
    __syncthreads();

    // O += P V   (thread cols d = tj*8 .. tj*8+7)
    for (int j2 = 0; j2 < 32; ++j2) {
      float2 pv[4];
#pragma unroll
      for (int r = 0; r < 4; ++r) pv[r] = bfp2f(ps[(ti * 4 + r) * PST + j2]);
      float2 va[4], vb[4];
#pragma unroll
      for (int c = 0; c < 4; ++c) {
        va[c] = bfp2f(vs[(2 * j2) * SST + tj * 4 + c]);
        vb[c] = bfp2f(vs[(2 * j2 + 1) * SST + tj * 4 + c]);
      }
#pragma unroll
      for (int r = 0; r < 4; ++r)
#pragma unroll
        for (int c = 0; c < 4; ++c) {
          o_acc[r][2 * c]     += pv[r].x * va[c].x + pv[r].y * vb[c].x;
          o_acc[r][2 * c + 1] += pv[r].x * va[c].y + pv[r].y * vb[c].y;
        }
    }
  }

#pragma unroll
  for (int r = 0; r < 4; ++r) {
    float invl = 1.0f / l_r[r];
    u32 wv[4];
#pragma unroll
    for (int q = 0; q < 4; ++q)
      wv[q] = f2bfp(o_acc[r][2 * q] * invl, o_acc[r][2 * q + 1] * invl);
    *reinterpret_cast<uint4*>(Om + (base + i0 + ti * 4 + r) * TK + tj * 8) =
        make_uint4(wv[0], wv[1], wv[2], wv[3]);
  }
}

// ============================================================
// Kernel 3: out[b][t2][kk] = sum_c Om[b][(c>>7)*2048 + t2][c&127] * Wut[c][kk] + bu[kk]
// Block: 256 thr, 16 rows. Grid 512.
// ============================================================
__global__ __launch_bounds__(256) void proj_kernel(
    const u16* __restrict__ Om, const float* __restrict__ Wut,
    const float* __restrict__ bu, float* __restrict__ out) {
  const int tid = threadIdx.x;
  const int R0 = blockIdx.x * 16;          // global row = b*2048 + t2
  const int b = R0 >> 11;
  const int t2_0 = R0 & 2047;

  __shared__ u16 os[16 * 1024];

  {
    uint4* od = reinterpret_cast<uint4*>(os);
    for (int li = tid; li < 2048; li += 256) {
      int lt = li >> 7, cq = li & 127;
      int gpd = cq >> 4, d = (cq & 15) * 8;
      od[li] = *reinterpret_cast<const uint4*>(
          Om + ((size_t)b * NM + (size_t)gpd * TT + (t2_0 + lt)) * TK + d);
    }
  }
  __syncthreads();

  const int kk = tid & 127, rg = tid >> 7;
  float acc[8];
  float bv = bu[kk];
#pragma unroll
  for (int rr = 0; rr < 8; ++rr) acc[rr] = bv;

  const u32* os2 = reinterpret_cast<const u32*>(os);
  for (int c2 = 0; c2 < 512; ++c2) {
    float w0 = Wut[(2 * c2) * TK + kk];
    float w1 = Wut[(2 * c2 + 1) * TK + kk];
#pragma unroll
    for (int rr = 0; rr < 8; ++rr) {
      float2 xv = bfp2f(os2[(rg * 8 + rr) * 512 + c2]);
      acc[rr] += xv.x * w0 + xv.y * w1;
    }
  }
#pragma unroll
  for (int rr = 0; rr < 8; ++rr)
    out[((size_t)b * TT + t2_0 + rg * 8 + rr) * TK + kk] = acc[rr];
}

// ============================================================
extern "C" void kernel_launch(void* const* d_in, const int* in_sizes, int n_in,
                              void* d_out, int out_size, void* d_ws, size_t ws_size,
                              hipStream_t stream) {
  const float* x  = (const float*)d_in[0];
  const float* Wq = (const float*)d_in[1];
  const float* bq = (const float*)d_in[2];
  const float* Wk = (const float*)d_in[3];
  const float* bk = (const float*)d_in[4];
  const float* Wv = (const float*)d_in[5];
  const float* Wu = (const float*)d_in[6];
  const float* bu = (const float*)d_in[7];
  float* out = (float*)d_out;

  char* ws = (char*)d_ws;
  float* Wqt = (float*)(ws + 0);          // 640*1024 f32
  float* Wkt = (float*)(ws + 2621440);    // 640*1024 f32
  float* Wvt = (float*)(ws + 5242880);    // 128*1024 f32
  float* Wut = (float*)(ws + 5767168);    // 1024*128 f32
  u16* Qm = (u16*)(ws + 6291456);         // 4*16384*128 bf16
  u16* Km = (u16*)(ws + 23068672);
  u16* Vm = (u16*)(ws + 39845888);
  u16* Om = (u16*)(ws + 56623104);        // total 73400320 bytes

  prep_kernel<<<2560, 256, 0, stream>>>(Wq, Wk, Wv, Wu, Wqt, Wkt, Wvt, Wut);
  qkv_kernel<<<dim3(64, 2, 4), 256, 0, stream>>>(x, Wqt, bq, Wkt, bk, Wvt, Qm, Km, Vm);
  attn_kernel<<<dim3(32, 8, 4), 256, 0, stream>>>(Qm, Km, Vm, Om);
  proj_kernel<<<512, 256, 0, stream>>>(Om, Wut, bu, out);
}

// Round 12
// 649.627 us; speedup vs baseline: 2.9425x; 2.9425x over previous
//
#include <hip/hip_runtime.h>

#define TK 128
#define TH 8
#define TB 4
#define TT 2048
#define NM (TT*TH)     // 16384 rows (m = t*8+h) per batch
#define KH 1024        // K*H output channels
#define KSZ 5

typedef unsigned int u32;
typedef unsigned short u16;
typedef unsigned long long u64;

typedef short bf16x8 __attribute__((ext_vector_type(8)));
typedef unsigned short us16x8 __attribute__((ext_vector_type(8)));
typedef float f32x4  __attribute__((ext_vector_type(4)));

// ---- bf16 <-> f32 helpers (bit-level) ----
__device__ __forceinline__ u16 f2bf(float f) {
  u32 u = __float_as_uint(f);
  u32 r = u + 0x7fffu + ((u >> 16) & 1u);   // round-to-nearest-even
  return (u16)(r >> 16);
}
__device__ __forceinline__ float2 bfp2f(u32 u) {
  return make_float2(__uint_as_float(u << 16), __uint_as_float(u & 0xffff0000u));
}
__device__ __forceinline__ u32 f2bfp(float lo, float hi) {
  return ((u32)f2bf(lo)) | (((u32)f2bf(hi)) << 16);
}

// async global->LDS, 16B per lane; LDS dest = wave-uniform base + lane*16
__device__ __forceinline__ void gload_lds16(const void* g, void* l) {
  __builtin_amdgcn_global_load_lds(
      (const __attribute__((address_space(1))) u32*)g,
      (__attribute__((address_space(3))) u32*)l, 16, 0, 0);
}

// one swizzle everywhere: XOR 16B-granule within the row by (row&7)
__device__ __forceinline__ int swz(int row) { return (row & 7) << 4; }

// ============================================================
// Kernel 0: weight transposes (channel-last for coalesced reads)
// ============================================================
__global__ void prep_kernel(const float* __restrict__ Wq, const float* __restrict__ Wk,
                            const float* __restrict__ Wv, const float* __restrict__ Wu,
                            float* __restrict__ Wqt, float* __restrict__ Wkt,
                            float* __restrict__ Wvt, float* __restrict__ Wut) {
  int idx = blockIdx.x * 256 + threadIdx.x;
  int ij = idx >> 10;
  int o  = idx & 1023;
  Wqt[idx] = Wq[o * (TK * KSZ) + ij];
  Wkt[idx] = Wk[o * (TK * KSZ) + ij];
  if (idx < TK * KH) {
    int i2 = idx >> 10;
    Wvt[idx] = Wv[o * TK + i2];
    int c = idx >> 7, kk = idx & 127;
    Wut[idx] = Wu[kk * KH + c];
  }
}

// ============================================================
// Kernel 1: causal conv QKV -> bf16 tensors in m-layout (HW-verified round 1)
// ============================================================
__device__ __forceinline__ void conv5_pass(
    const float (*xs)[TK], u16* ys, const float* __restrict__ Wt,
    const float* __restrict__ bias, u16* __restrict__ dst,
    float outscale, int tid, int half, int t0, int b) {
  const int oc0 = half * 512 + tid;
  float acc[2][32];
#pragma unroll
  for (int c = 0; c < 2; ++c) {
    float bv = bias[oc0 + c * 256];
#pragma unroll
    for (int t = 0; t < 32; ++t) acc[c][t] = bv;
  }
  for (int i = 0; i < TK; ++i) {
    float xv[36];
#pragma unroll
    for (int r = 0; r < 36; ++r) xv[r] = xs[r][i];
#pragma unroll
    for (int c = 0; c < 2; ++c) {
      const float* wp = Wt + (size_t)(i * KSZ) * KH + oc0 + c * 256;
#pragma unroll
      for (int j = 0; j < KSZ; ++j) {
        float w = wp[j * KH];
#pragma unroll
        for (int t = 0; t < 32; ++t) acc[c][t] += xv[t + j] * w;
      }
    }
  }
#pragma unroll
  for (int c = 0; c < 2; ++c) {
    int oc = oc0 + c * 256;
    int dl = (oc >> 3) - half * 64, h = oc & 7;
#pragma unroll
    for (int t = 0; t < 32; ++t)
      ys[(t * 8 + h) * 64 + dl] = f2bf(acc[c][t] * outscale);
  }
  __syncthreads();
  const uint4* ysv = reinterpret_cast<const uint4*>(ys);
  for (int li = tid; li < 2048; li += 256) {
    int row = li >> 3, dcol = (li & 7) * 8;
    *reinterpret_cast<uint4*>(dst + ((size_t)b * NM + t0 * 8 + row) * TK + half * 64 + dcol) = ysv[li];
  }
  __syncthreads();
}

__device__ __forceinline__ void conv1_pass(
    const float (*xs)[TK], u16* ys, const float* __restrict__ Wt,
    u16* __restrict__ dst, int tid, int half, int t0, int b) {
  const int oc0 = half * 512 + tid;
  float acc[2][32];
#pragma unroll
  for (int c = 0; c < 2; ++c)
#pragma unroll
    for (int t = 0; t < 32; ++t) acc[c][t] = 0.0f;
  for (int i = 0; i < TK; ++i) {
    float xv[32];
#pragma unroll
    for (int r = 0; r < 32; ++r) xv[r] = xs[r + 4][i];
#pragma unroll
    for (int c = 0; c < 2; ++c) {
      float w = Wt[(size_t)i * KH + oc0 + c * 256];
#pragma unroll
      for (int t = 0; t < 32; ++t) acc[c][t] += xv[t] * w;
    }
  }
#pragma unroll
  for (int c = 0; c < 2; ++c) {
    int oc = oc0 + c * 256;
    int dl = (oc >> 3) - half * 64, h = oc & 7;
#pragma unroll
    for (int t = 0; t < 32; ++t)
      ys[(t * 8 + h) * 64 + dl] = f2bf(acc[c][t]);
  }
  __syncthreads();
  const uint4* ysv = reinterpret_cast<const uint4*>(ys);
  for (int li = tid; li < 2048; li += 256) {
    int row = li >> 3, dcol = (li & 7) * 8;
    *reinterpret_cast<uint4*>(dst + ((size_t)b * NM + t0 * 8 + row) * TK + half * 64 + dcol) = ysv[li];
  }
  __syncthreads();
}

__global__ __launch_bounds__(256) void qkv_kernel(
    const float* __restrict__ x,
    const float* __restrict__ Wqt, const float* __restrict__ bq,
    const float* __restrict__ Wkt, const float* __restrict__ bk,
    const float* __restrict__ Wvt,
    u16* __restrict__ Qm, u16* __restrict__ Km, u16* __restrict__ Vm) {
  const int tid = threadIdx.x;
  const int t0 = blockIdx.x * 32;
  const int half = blockIdx.y;
  const int b = blockIdx.z;

  __shared__ float xs[36][TK];
  __shared__ u16 ys[256 * 64];

  for (int li = tid; li < 36 * TK; li += 256) {
    int rr = li >> 7, col = li & 127;
    int t = t0 - 4 + rr;
    xs[rr][col] = (t >= 0) ? x[((size_t)b * TT + t) * TK + col] : 0.0f;
  }
  __syncthreads();

  const float inv_scale = 0.29730177875068026f;   // 128^-0.25
  conv5_pass(xs, ys, Wqt, bq, Qm, inv_scale, tid, half, t0, b);
  conv5_pass(xs, ys, Wkt, bk, Km, inv_scale, tid, half, t0, b);
  conv1_pass(xs, ys, Wvt, Vm, tid, half, t0, b);
}

// ============================================================
// Kernel 2: MFMA flash attention v2 — de-risked.
//   K: gload_lds + pre-swizzled source (m173 pattern), bf16x8 B-frags.
//   V: reg-staged TRANSPOSE into Vt[128 d][64 kv] (scalar ds_write scatter,
//      wave-uniform row per step -> conflict-free), bf16x8 B-frags like K.
//   P: natural kv order, 4 scalar u16 stores/row, bf16x8 A-frag reads.
//   No ds_read_b64_tr_b16, no kv-slot permutation.
// ============================================================
#define QBLK 128
#define KVBLK 64

__global__ __launch_bounds__(256, 2) void attn_kernel(
    const u16* __restrict__ Qm, const u16* __restrict__ Km,
    const u16* __restrict__ Vm, u16* __restrict__ Om) {
  __shared__ __align__(16) char smem[49152];
  char* ksm = smem;            // 16KB: K  [64 kv][256B],  swz-paired
  char* vsm = smem + 16384;    // 16KB: Vt [128 d][128B],  swz-paired
  char* psm = smem + 32768;    // 16KB: P  [128 row][128B], swz-paired

  const int tid  = threadIdx.x;
  const int lane = tid & 63;
  const int w    = tid >> 6;
  const int g    = lane >> 4;
  const int c    = lane & 15;

  const int it = 15 - (int)blockIdx.x;       // big blocks dispatched first
  const int gp = blockIdx.y, b = blockIdx.z;
  const size_t base = (size_t)b * NM + (size_t)gp * TT;
  const int i0 = it * QBLK;

  const u16* Qg = Qm + (base + i0) * TK;
  const u16* Kg = Km + base * TK;
  const u16* Vg = Vm + base * TK;

  // ---- Q fragments in registers: rows w*32+rg*16+c, k = ks*32+g*8 ----
  bf16x8 qf[2][4];
#pragma unroll
  for (int rg = 0; rg < 2; ++rg)
#pragma unroll
    for (int ks = 0; ks < 4; ++ks)
      qf[rg][ks] = *(const bf16x8*)(Qg + (size_t)(w*32 + rg*16 + c) * TK + ks*32 + g*8);

  f32x4 oacc[2][8];
  float m_r[2][4], l_r[2][4];
#pragma unroll
  for (int rg = 0; rg < 2; ++rg) {
#pragma unroll
    for (int r = 0; r < 4; ++r) { m_r[rg][r] = -1e30f; l_r[rg][r] = 0.0f; }
#pragma unroll
    for (int dg = 0; dg < 8; ++dg) oacc[rg][dg] = (f32x4){0.f,0.f,0.f,0.f};
  }

  const int njt = 2*it + 2;
  const int wrow0 = i0 + w*32;                      // wave's first q row

  for (int jt = 0; jt < njt; ++jt) {
    const int j0 = jt * KVBLK;

    // ---- stage K via gload_lds (pre-swizzled source, linear LDS dest) ----
#pragma unroll
    for (int q = 0; q < 4; ++q) {
      const int ck = w*4 + q;
      int row = ck*4 + g;                  // lds byte = ck*1024 + lane*16
      gload_lds16((const char*)(Kg + (size_t)(j0+row)*TK) + ((c*16) ^ swz(row)),
                  ksm + ck*1024);
    }

    // ---- stage Vt: reg-staged transpose. lane = kv, wave w owns d-range
    //      [w*32, w*32+32). Per write step all 64 lanes hit one row -> free.
    {
      const u16* vrow = Vg + (size_t)(j0 + lane) * TK + w*32;
#pragma unroll
      for (int it2 = 0; it2 < 4; ++it2) {
        us16x8 vv = *(const us16x8*)(vrow + it2*8);
#pragma unroll
        for (int i = 0; i < 8; ++i) {
          int d = w*32 + it2*8 + i;
          *(u16*)(vsm + d*128 + ((lane*2) ^ swz(d))) = vv[i];
        }
      }
    }
    __syncthreads();

    if (j0 <= wrow0 + 31) {     // wave has unmasked columns in this tile
      // ---- S = Q K^T ----
      f32x4 sacc[2][4];
#pragma unroll
      for (int rg = 0; rg < 2; ++rg)
#pragma unroll
        for (int cg = 0; cg < 4; ++cg) sacc[rg][cg] = (f32x4){0.f,0.f,0.f,0.f};

#pragma unroll
      for (int cg = 0; cg < 4; ++cg) {
        bf16x8 kf[4];
#pragma unroll
        for (int ks = 0; ks < 4; ++ks) {
          int row  = cg*16 + c;
          int colb = ks*64 + g*16;
          kf[ks] = *(const bf16x8*)(ksm + row*256 + (colb ^ swz(row)));
        }
#pragma unroll
        for (int rg = 0; rg < 2; ++rg)
#pragma unroll
          for (int ks = 0; ks < 4; ++ks)
            sacc[rg][cg] = __builtin_amdgcn_mfma_f32_16x16x32_bf16(
                qf[rg][ks], kf[ks], sacc[rg][cg], 0, 0, 0);
      }

      // ---- diagonal causal mask (C/D: col=lane&15, row=(lane>>4)*4+reg) ----
      if (j0 + KVBLK - 1 > wrow0) {
#pragma unroll
        for (int rg = 0; rg < 2; ++rg)
#pragma unroll
          for (int cg = 0; cg < 4; ++cg) {
            int jv = j0 + cg*16 + c;
#pragma unroll
            for (int r = 0; r < 4; ++r) {
              int iv = wrow0 + rg*16 + g*4 + r;
              if (jv > iv) sacc[rg][cg][r] = -1e30f;
            }
          }
      }

      // ---- online softmax + P staging (natural kv order, scalar stores) ----
#pragma unroll
      for (int rg = 0; rg < 2; ++rg)
#pragma unroll
        for (int r = 0; r < 4; ++r) {
          float s0 = sacc[rg][0][r], s1 = sacc[rg][1][r];
          float s2 = sacc[rg][2][r], s3 = sacc[rg][3][r];
          float tm = fmaxf(fmaxf(s0, s1), fmaxf(s2, s3));
          tm = fmaxf(tm, __shfl_xor(tm, 1));
          tm = fmaxf(tm, __shfl_xor(tm, 2));
          tm = fmaxf(tm, __shfl_xor(tm, 4));
          tm = fmaxf(tm, __shfl_xor(tm, 8));
          float mold = m_r[rg][r];
          float mnew = fmaxf(mold, tm);
          float alpha = __expf(mold - mnew);
          float p0 = __expf(s0 - mnew), p1 = __expf(s1 - mnew);
          float p2 = __expf(s2 - mnew), p3 = __expf(s3 - mnew);
          float psum = p0 + p1 + p2 + p3;
          psum += __shfl_xor(psum, 1);
          psum += __shfl_xor(psum, 2);
          psum += __shfl_xor(psum, 4);
          psum += __shfl_xor(psum, 8);
          l_r[rg][r] = l_r[rg][r] * alpha + psum;
          m_r[rg][r] = mnew;
#pragma unroll
          for (int dg = 0; dg < 8; ++dg) oacc[rg][dg][r] *= alpha;
          int row = w*32 + rg*16 + g*4 + r;
          char* prow = psm + row*128;
          int sw = swz(row);
          *(u16*)(prow + (((c     ) * 2) ^ sw)) = f2bf(p0);   // kv = 0*16+c
          *(u16*)(prow + (((c + 16) * 2) ^ sw)) = f2bf(p1);   // kv = 1*16+c
          *(u16*)(prow + (((c + 32) * 2) ^ sw)) = f2bf(p2);   // kv = 2*16+c
          *(u16*)(prow + (((c + 48) * 2) ^ sw)) = f2bf(p3);   // kv = 3*16+c
        }

      // Compiler fence: u16 P-stores above vs bf16x8 P-loads below are
      // differently-typed LDS accesses (TBAA may sink the store). HW DS pipe
      // is in-order per wave, so a zero-cost ordering fence suffices.
      asm volatile("" ::: "memory");

      // ---- O += P V : A-frag = P[row=..+c][kv=ks2*32+g*8..+7],
      //                 B-frag = Vt[dcol=dg*16+c][kv=ks2*32+g*8..+7] ----
      bf16x8 pf[2][2];
#pragma unroll
      for (int rg = 0; rg < 2; ++rg)
#pragma unroll
        for (int ks2 = 0; ks2 < 2; ++ks2) {
          int row = w*32 + rg*16 + c;
          pf[rg][ks2] = *(const bf16x8*)(psm + row*128 + ((ks2*64 + g*16) ^ swz(row)));
        }

#pragma unroll
      for (int dg = 0; dg < 8; ++dg) {
        bf16x8 vf[2];
#pragma unroll
        for (int ks2 = 0; ks2 < 2; ++ks2) {
          int drow = dg*16 + c;
          vf[ks2] = *(const bf16x8*)(vsm + drow*128 + ((ks2*64 + g*16) ^ swz(drow)));
        }
#pragma unroll
        for (int rg = 0; rg < 2; ++rg) {
          oacc[rg][dg] = __builtin_amdgcn_mfma_f32_16x16x32_bf16(
              pf[rg][0], vf[0], oacc[rg][dg], 0, 0, 0);
          oacc[rg][dg] = __builtin_amdgcn_mfma_f32_16x16x32_bf16(
              pf[rg][1], vf[1], oacc[rg][dg], 0, 0, 0);
        }
      }
    }
    __syncthreads();
  }

  // ---- epilogue: O = oacc / l, paired bf16 stores ----
#pragma unroll
  for (int rg = 0; rg < 2; ++rg)
#pragma unroll
    for (int r = 0; r < 4; ++r) {
      float invl = 1.0f / l_r[rg][r];
      int row = i0 + w*32 + rg*16 + g*4 + r;
      u16* orow = Om + (base + row) * TK;
#pragma unroll
      for (int dg = 0; dg < 8; ++dg) {
        float v0 = oacc[rg][dg][r] * invl;
        float v1 = __shfl_xor(v0, 1);
        if (!(lane & 1))
          *(u32*)(orow + dg*16 + c) = f2bfp(v0, v1);
      }
    }
}

// ============================================================
// Kernel 3: output projection (HW-verified round 1)
// ============================================================
__global__ __launch_bounds__(256) void proj_kernel(
    const u16* __restrict__ Om, const float* __restrict__ Wut,
    const float* __restrict__ bu, float* __restrict__ out) {
  const int tid = threadIdx.x;
  const int R0 = blockIdx.x * 16;
  const int b = R0 >> 11;
  const int t2_0 = R0 & 2047;

  __shared__ u16 os[16 * 1024];

  {
    uint4* od = reinterpret_cast<uint4*>(os);
    for (int li = tid; li < 2048; li += 256) {
      int lt = li >> 7, cq = li & 127;
      int gpd = cq >> 4, d = (cq & 15) * 8;
      od[li] = *reinterpret_cast<const uint4*>(
          Om + ((size_t)b * NM + (size_t)gpd * TT + (t2_0 + lt)) * TK + d);
    }
  }
  __syncthreads();

  const int kk = tid & 127, rg = tid >> 7;
  float acc[8];
  float bv = bu[kk];
#pragma unroll
  for (int rr = 0; rr < 8; ++rr) acc[rr] = bv;

  const u32* os2 = reinterpret_cast<const u32*>(os);
  for (int c2 = 0; c2 < 512; ++c2) {
    float w0 = Wut[(2 * c2) * TK + kk];
    float w1 = Wut[(2 * c2 + 1) * TK + kk];
#pragma unroll
    for (int rr = 0; rr < 8; ++rr) {
      float2 xv = bfp2f(os2[(rg * 8 + rr) * 512 + c2]);
      acc[rr] += xv.x * w0 + xv.y * w1;
    }
  }
#pragma unroll
  for (int rr = 0; rr < 8; ++rr)
    out[((size_t)b * TT + t2_0 + rg * 8 + rr) * TK + kk] = acc[rr];
}

// ============================================================
extern "C" void kernel_launch(void* const* d_in, const int* in_sizes, int n_in,
                              void* d_out, int out_size, void* d_ws, size_t ws_size,
                              hipStream_t stream) {
  const float* x  = (const float*)d_in[0];
  const float* Wq = (const float*)d_in[1];
  const float* bq = (const float*)d_in[2];
  const float* Wk = (const float*)d_in[3];
  const float* bk = (const float*)d_in[4];
  const float* Wv = (const float*)d_in[5];
  const float* Wu = (const float*)d_in[6];
  const float* bu = (const float*)d_in[7];
  float* out = (float*)d_out;

  char* ws = (char*)d_ws;
  float* Wqt = (float*)(ws + 0);          // 640*1024 f32
  float* Wkt = (float*)(ws + 2621440);
  float* Wvt = (float*)(ws + 5242880);
  float* Wut = (float*)(ws + 5767168);
  u16* Qm = (u16*)(ws + 6291456);         // 4*16384*128 bf16
  u16* Km = (u16*)(ws + 23068672);
  u16* Vm = (u16*)(ws + 39845888);
  u16* Om = (u16*)(ws + 56623104);

  prep_kernel<<<2560, 256, 0, stream>>>(Wq, Wk, Wv, Wu, Wqt, Wkt, Wvt, Wut);
  qkv_kernel<<<dim3(64, 2, 4), 256, 0, stream>>>(x, Wqt, bq, Wkt, bk, Wvt, Qm, Km, Vm);
  attn_kernel<<<dim3(16, 8, 4), 256, 0, stream>>>(Qm, Km, Vm, Om);
  proj_kernel<<<512, 256, 0, stream>>>(Om, Wut, bu, out);
}